// Round 2
// baseline (2947.171 us; speedup 1.0000x reference)
//
#include <hip/hip_runtime.h>

#define THREADS 256
#define BT 16
#define TLEN 512
#define HD 128
#define NT 8   // 16-col N-tiles per wave (4 waves x 128 cols = 512 gate cols)

typedef __attribute__((ext_vector_type(8))) short bf16x8;
typedef __attribute__((ext_vector_type(4))) float f32x4;

__device__ __forceinline__ short f2bf(float f) {
  unsigned u = __float_as_uint(f);
  u += 0x7fff + ((u >> 16) & 1);
  return (short)(u >> 16);
}

__device__ __forceinline__ float fsig(float x) {
  return __builtin_amdgcn_rcpf(1.0f + __builtin_amdgcn_exp2f(-1.4426950408889634f * x));
}
__device__ __forceinline__ float ftanh(float x) {
  return 1.0f - 2.0f * __builtin_amdgcn_rcpf(1.0f + __builtin_amdgcn_exp2f(2.8853900817779268f * x));
}

__device__ __forceinline__ bf16x8 pack8(f32x4 a, f32x4 b) {
  bf16x8 r;
  r[0]=f2bf(a[0]); r[1]=f2bf(a[1]); r[2]=f2bf(a[2]); r[3]=f2bf(a[3]);
  r[4]=f2bf(b[0]); r[5]=f2bf(b[1]); r[6]=f2bf(b[2]); r[7]=f2bf(b[3]);
  return r;
}
__device__ __forceinline__ bf16x8 load8(const float* p) {
  const f32x4* q4 = (const f32x4*)p;
  return pack8(q4[0], q4[1]);
}

// 4x4 transpose across (lane&3, reg) within each quad of lanes.
__device__ __forceinline__ void quad_transpose(float& v0, float& v1, float& v2, float& v3, int l) {
  const bool l0 = (l & 1) != 0, l1 = (l & 2) != 0;
  float s, r;
  s = l0 ? v0 : v1; r = __shfl_xor(s, 1, 64); if (l0) v0 = r; else v1 = r;
  s = l0 ? v2 : v3; r = __shfl_xor(s, 1, 64); if (l0) v2 = r; else v3 = r;
  s = l1 ? v0 : v2; r = __shfl_xor(s, 2, 64); if (l1) v0 = r; else v2 = r;
  s = l1 ? v1 : v3; r = __shfl_xor(s, 2, 64); if (l1) v1 = r; else v3 = r;
}

// 4 waves, 1 wave/SIMD -> up to 512 unified VGPR+AGPR per wave.
__global__ __launch_bounds__(THREADS, 1) void lstm_kernel(
    const float* __restrict__ xg,
    const float* __restrict__ Wih0, const float* __restrict__ Whh0,
    const float* __restrict__ bih0, const float* __restrict__ bhh0,
    const float* __restrict__ Wih1, const float* __restrict__ Whh1,
    const float* __restrict__ bih1, const float* __restrict__ bhh1,
    const float* __restrict__ gma, const float* __restrict__ bta,
    const float* __restrict__ mu,  const float* __restrict__ var,
    const float* __restrict__ W1,  const float* __restrict__ b1,
    const float* __restrict__ W2,  const float* __restrict__ b2,
    const float* __restrict__ Wf,  const float* __restrict__ bfv,
    const int* __restrict__ psP,
    float* __restrict__ dout)
{
  // ---- LDS ----
  __shared__ __align__(16) short xA[BT*32];        // [b][k0..31], col8 = 1.0 (bias), rest 0
  __shared__ __align__(16) short h0A[2][BT*136];   // bf16 A-layout, padded rows
  __shared__ __align__(16) short h1A[2][BT*136];
  __shared__ __align__(16) short wih0L[512*32];    // [col][k0..31]: Wih0, bias col8, zeros k>=9
  __shared__ __align__(16) short W1B[4*4*64*8];    // s*W1 bf16, frag-ordered [w][kk][lane][8]
  __shared__ float sLs[HD];
  __shared__ float a1L[64*BT];
  __shared__ float outL[4*BT];
  __shared__ float W2L[4*65];
  __shared__ float WfL[8*4];
  __shared__ float b2L[4];
  __shared__ float bfL[8];
  __shared__ float b1cL[64];

  const int tid = threadIdx.x;
  const int w   = tid >> 6;      // wave 0..3, owns gate cols [128w, 128w+128)
  const int l   = tid & 63;
  const int ln  = l & 15;
  const int q   = l >> 4;
  const int gb0 = blockIdx.x * BT;
  const int ps  = psP[0];

  // ---- init LDS ----
  for (int i = tid; i < BT*32; i += THREADS) xA[i] = 0;
  for (int i = tid; i < BT*136; i += THREADS) {
    h0A[0][i] = 0; h0A[1][i] = 0; h1A[0][i] = 0; h1A[1][i] = 0;
  }
  if (tid < BT) xA[tid*32 + 8] = (short)0x3F80;   // 1.0 bf16 -> layer0 bias slot
  if (tid < HD) sLs[tid] = gma[tid] * rsqrtf(var[tid] + 1e-5f);
  for (int i = tid; i < 260; i += THREADS) { int o = i / 65, p = i % 65; W2L[i] = (p < 64) ? W2[o*64 + p] : 0.f; }
  if (tid < 32) WfL[tid] = Wf[tid];
  if (tid < 4)  b2L[tid] = b2[tid];
  if (tid < 8)  bfL[tid] = bfv[tid];
  for (int i = tid; i < 512*32; i += THREADS) {
    int col = i >> 5, k = i & 31;
    int og = (col & 3)*HD + (col >> 2);            // gate-permuted row
    float v = 0.f;
    if (k < 8) v = Wih0[og*8 + k];
    else if (k == 8) v = bih0[og] + bhh0[og];
    wih0L[i] = f2bf(v);
  }
  __syncthreads();  // sLs ready
  if (tid < 64) {
    float acc = b1[tid];
    for (int j = 0; j < HD; j++)
      acc += (bta[j] - mu[j]*sLs[j]) * W1[tid*HD + j];
    b1cL[tid] = acc;
  }
  for (int i = tid; i < 4*4*64*8; i += THREADS) {
    int j = i & 7, lw = (i >> 3) & 63, kk = (i >> 9) & 3, wv = i >> 11;
    int nn = lw & 15, qq = lw >> 4;
    int k = kk*32 + qq*8 + j;
    int p = wv*16 + nn;
    W1B[i] = f2bf(sLs[k] * W1[p*HD + k]);
  }

  // ---- register-resident weight fragments (bf16), gate-permuted ----
  bf16x8 whh0f[NT][4], wih1f[NT][4], whh1f[NT][4];
  float b1sum[NT];
  #pragma unroll
  for (int nt = 0; nt < NT; nt++) {
    int col = w*128 + nt*16 + ln;
    int og  = (col & 3)*HD + (col >> 2);
    #pragma unroll
    for (int kk = 0; kk < 4; kk++) {
      int k0 = kk*32 + q*8;
      whh0f[nt][kk] = load8(Whh0 + og*HD + k0);
      wih1f[nt][kk] = load8(Wih1 + og*HD + k0);
      whh1f[nt][kk] = load8(Whh1 + og*HD + k0);
    }
    b1sum[nt] = bih1[og] + bhh1[og];
  }
  __syncthreads();  // all LDS init done

  float c0s[NT], c1s[NT];
  #pragma unroll
  for (int nt = 0; nt < NT; nt++) { c0s[nt] = 0.f; c1s[nt] = 0.f; }

  const int aoffX = ln*32  + q*8;   // x A-frag offset (shorts)
  const int aoffH = ln*136 + q*8;   // h A-frag offset, + kk*32
  const int mrow  = q*4 + (l & 3);  // row after quad-transpose
  const int jbase = w*32 + ((l >> 2) & 3);

  // -------- layer 0: z = x@Wih0^T (+bias via col8) + h0@Whh0^T --------
  auto layer0 = [&](const short* h0r, short* h0w) {
    bf16x8 ax = *(const bf16x8*)(xA + aoffX);
    bf16x8 ah[4];
    #pragma unroll
    for (int kk = 0; kk < 4; kk++)
      ah[kk] = *(const bf16x8*)(h0r + aoffH + kk*32);
    #pragma unroll
    for (int nt = 0; nt < NT; nt++) {
      bf16x8 wf = *(const bf16x8*)(wih0L + (w*128 + nt*16 + ln)*32 + q*8);
      f32x4 a = {0.f,0.f,0.f,0.f};
      a = __builtin_amdgcn_mfma_f32_16x16x32_bf16(ax, wf, a, 0, 0, 0);
      #pragma unroll
      for (int kk = 0; kk < 4; kk++)
        a = __builtin_amdgcn_mfma_f32_16x16x32_bf16(ah[kk], whh0f[nt][kk], a, 0, 0, 0);
      float v0 = a[0], v1 = a[1], v2 = a[2], v3 = a[3];
      quad_transpose(v0, v1, v2, v3, l);
      float ii = fsig(v0), ff = fsig(v1), gg = ftanh(v2), oo = fsig(v3);
      float c = ff*c0s[nt] + ii*gg;
      c0s[nt] = c;
      float h = oo * ftanh(c);
      h0w[mrow*136 + jbase + nt*4] = f2bf(h);
    }
  };

  // -------- layer 1: z = h0new@Wih1^T + h1@Whh1^T + b --------
  auto layer1 = [&](const short* h0n, const short* h1r, short* h1w) {
    bf16x8 a0[4], a1k[4];
    #pragma unroll
    for (int kk = 0; kk < 4; kk++) {
      a0[kk]  = *(const bf16x8*)(h0n + aoffH + kk*32);
      a1k[kk] = *(const bf16x8*)(h1r + aoffH + kk*32);
    }
    #pragma unroll
    for (int nt = 0; nt < NT; nt++) {
      f32x4 a; a[0]=a[1]=a[2]=a[3]=b1sum[nt];
      #pragma unroll
      for (int kk = 0; kk < 4; kk++) {
        a = __builtin_amdgcn_mfma_f32_16x16x32_bf16(a0[kk],  wih1f[nt][kk], a, 0, 0, 0);
        a = __builtin_amdgcn_mfma_f32_16x16x32_bf16(a1k[kk], whh1f[nt][kk], a, 0, 0, 0);
      }
      float v0 = a[0], v1 = a[1], v2 = a[2], v3 = a[3];
      quad_transpose(v0, v1, v2, v3, l);
      float ii = fsig(v0), ff = fsig(v1), gg = ftanh(v2), oo = fsig(v3);
      float c = ff*c1s[nt] + ii*gg;
      c1s[nt] = c;
      float h = oo * ftanh(c);
      h1w[mrow*136 + jbase + nt*4] = f2bf(h);
    }
  };

  // ================= encoder (x[t+1] prefetched under layer0) =================
  // preload x[0]
  {
    const int b = tid >> 3, i = tid & 7;
    if (tid < 128) xA[b*32 + i] = f2bf(xg[(size_t)(gb0 + b)*(TLEN*8) + 0*8 + i]);
    __syncthreads();
  }
  auto enc_iter = [&](int tt, const short* h0r, short* h0w, const short* h1r, short* h1w) {
    const int b = tid >> 3, i = tid & 7;
    const bool pf = (tt + 1 < TLEN) && (tid < 128);
    float xp = 0.f;
    if (pf) xp = xg[(size_t)(gb0 + b)*(TLEN*8) + (tt+1)*8 + i];   // in flight under layer0
    layer0(h0r, h0w);
    __syncthreads();           // h0 new visible; all layer0 xA reads done
    if (pf) xA[b*32 + i] = f2bf(xp);
    layer1(h0w, h1r, h1w);
    __syncthreads();           // h1 new + xA(t+1) visible
  };
  for (int t = 0; t < TLEN; t += 2) {
    enc_iter(t,     h0A[0], h0A[1], h1A[0], h1A[1]);
    enc_iter(t + 1, h0A[1], h0A[0], h1A[1], h1A[0]);
  }
  // xA still holds x[:, T-1, :] == first decoder input; current state in buffers [0].

  // ================= decoder =================
  for (int s = 0; s < ps; s++) {
    int rb = s & 1;
    __syncthreads();  // xA + buffer turnover ready
    layer0(h0A[rb], h0A[rb^1]);
    __syncthreads();
    layer1(h0A[rb^1], h1A[rb], h1A[rb^1]);
    const short* h1n = h1A[rb^1];
    __syncthreads();  // h1 new visible to all waves
    // ---- a1 = relu((h1) @ (bn-folded W1)^T + b1c): MFMA on all 4 waves
    {
      f32x4 aa = {0.f,0.f,0.f,0.f};
      #pragma unroll
      for (int kk = 0; kk < 4; kk++) {
        bf16x8 ahn = *(const bf16x8*)(h1n + aoffH + kk*32);
        bf16x8 bw  = *(const bf16x8*)(W1B + ((w*4 + kk)*64 + l)*8);
        aa = __builtin_amdgcn_mfma_f32_16x16x32_bf16(ahn, bw, aa, 0, 0, 0);
      }
      float bb = b1cL[w*16 + ln];
      #pragma unroll
      for (int r = 0; r < 4; r++)
        a1L[(w*16 + ln)*16 + q*4 + r] = fmaxf(aa[r] + bb, 0.f);
    }
    __syncthreads();
    // ---- out = a1 @ W2^T + b2 ; store
    if (tid < 64) {
      int b = tid & 15, o = tid >> 4;
      float acc2 = b2L[o];
      for (int p = 0; p < 64; p++)
        acc2 += a1L[p*16 + b] * W2L[o*65 + p];
      dout[(size_t)(gb0 + b)*(ps*4) + s*4 + o] = acc2;
      outL[o*16 + b] = acc2;
    }
    __syncthreads();
    // ---- xin = out @ Wf^T + bf -> next x
    if (tid < 128) {
      int b = tid >> 3, i = tid & 7;
      float v = bfL[i];
      #pragma unroll
      for (int o = 0; o < 4; o++) v += outL[o*16 + b] * WfL[i*4 + o];
      xA[b*32 + i] = f2bf(v);
    }
  }
}

extern "C" void kernel_launch(void* const* d_in, const int* in_sizes, int n_in,
                              void* d_out, int out_size, void* d_ws, size_t ws_size,
                              hipStream_t stream) {
  (void)in_sizes; (void)n_in; (void)d_ws; (void)ws_size; (void)out_size;
  lstm_kernel<<<dim3(4096/BT), dim3(THREADS), 0, stream>>>(
      (const float*)d_in[0],  (const float*)d_in[1],  (const float*)d_in[2],
      (const float*)d_in[3],  (const float*)d_in[4],  (const float*)d_in[5],
      (const float*)d_in[6],  (const float*)d_in[7],  (const float*)d_in[8],
      (const float*)d_in[9],  (const float*)d_in[10], (const float*)d_in[11],
      (const float*)d_in[12], (const float*)d_in[13], (const float*)d_in[14],
      (const float*)d_in[15], (const float*)d_in[16], (const float*)d_in[17],
      (const float*)d_in[18], (const int*)d_in[19],   (float*)d_out);
}

// Round 3
// 1848.237 us; speedup vs baseline: 1.5946x; 1.5946x over previous
//
#include <hip/hip_runtime.h>

#define THREADS 512
#define BT 16
#define TLEN 512
#define HD 128
#define NT 4      // 16-col N-tiles per wave (8 waves x 64 cols = 512 gate cols)
#define WSTR 132  // WhhL col stride in shorts (264 B: 2-way max on b128 reads)
#define HSTR 136  // h row stride in shorts

typedef __attribute__((ext_vector_type(8))) short bf16x8;
typedef __attribute__((ext_vector_type(4))) float f32x4;

__device__ __forceinline__ short f2bf(float f) {
  unsigned u = __float_as_uint(f);
  u += 0x7fff + ((u >> 16) & 1);
  return (short)(u >> 16);
}

__device__ __forceinline__ float fsig(float x) {
  return __builtin_amdgcn_rcpf(1.0f + __builtin_amdgcn_exp2f(-1.4426950408889634f * x));
}
__device__ __forceinline__ float ftanh(float x) {
  return 1.0f - 2.0f * __builtin_amdgcn_rcpf(1.0f + __builtin_amdgcn_exp2f(2.8853900817779268f * x));
}

__device__ __forceinline__ bf16x8 pack8(f32x4 a, f32x4 b) {
  bf16x8 r;
  r[0]=f2bf(a[0]); r[1]=f2bf(a[1]); r[2]=f2bf(a[2]); r[3]=f2bf(a[3]);
  r[4]=f2bf(b[0]); r[5]=f2bf(b[1]); r[6]=f2bf(b[2]); r[7]=f2bf(b[3]);
  return r;
}
__device__ __forceinline__ bf16x8 load8(const float* p) {
  const f32x4* q4 = (const f32x4*)p;
  return pack8(q4[0], q4[1]);
}

// 4x4 transpose across (lane&3, reg) within each quad of lanes.
__device__ __forceinline__ void quad_transpose(float& v0, float& v1, float& v2, float& v3, int l) {
  const bool l0 = (l & 1) != 0, l1 = (l & 2) != 0;
  float s, r;
  s = l0 ? v0 : v1; r = __shfl_xor(s, 1, 64); if (l0) v0 = r; else v1 = r;
  s = l0 ? v2 : v3; r = __shfl_xor(s, 1, 64); if (l0) v2 = r; else v3 = r;
  s = l1 ? v0 : v2; r = __shfl_xor(s, 2, 64); if (l1) v0 = r; else v2 = r;
  s = l1 ? v1 : v3; r = __shfl_xor(s, 2, 64); if (l1) v1 = r; else v3 = r;
}

// 8 waves, 2 waves/SIMD -> 256 unified regs/wave. Per-wave reg weights ~160.
__global__ __launch_bounds__(THREADS, 2) void lstm_kernel(
    const float* __restrict__ xg,
    const float* __restrict__ Wih0, const float* __restrict__ Whh0,
    const float* __restrict__ bih0, const float* __restrict__ bhh0,
    const float* __restrict__ Wih1, const float* __restrict__ Whh1,
    const float* __restrict__ bih1, const float* __restrict__ bhh1,
    const float* __restrict__ gma, const float* __restrict__ bta,
    const float* __restrict__ mu,  const float* __restrict__ var,
    const float* __restrict__ W1,  const float* __restrict__ b1,
    const float* __restrict__ W2,  const float* __restrict__ b2,
    const float* __restrict__ Wf,  const float* __restrict__ bfv,
    const int* __restrict__ psP,
    float* __restrict__ dout)
{
  // ---- LDS (159,936 B of 163,840) ----
  __shared__ __align__(16) short WhhL[512*WSTR];   // Whh0, gate-permuted cols [col][k]
  __shared__ __align__(16) short h0A[2][BT*HSTR];  // bf16 A-layout
  __shared__ __align__(16) short h1A[2][BT*HSTR];
  __shared__ __align__(16) short xA[BT*32];        // [b][k0..31], col8 = 1.0 (bias)
  __shared__ float a1L[64*BT];
  __shared__ float W2L[4*65];
  __shared__ float outL[4*BT];
  __shared__ float WfL[8*4];
  __shared__ float b2L[4];
  __shared__ float bfL[8];
  __shared__ float b1cL[64];
  __shared__ float sLs[HD];

  const int tid = threadIdx.x;
  const int w   = tid >> 6;      // wave 0..7, owns gate cols [64w, 64w+64)
  const int l   = tid & 63;
  const int ln  = l & 15;
  const int q   = l >> 4;
  const int gb0 = blockIdx.x * BT;
  const int ps  = psP[0];

  // ---- init LDS phase A ----
  for (int i = tid; i < BT*32; i += THREADS) xA[i] = 0;
  for (int i = tid; i < BT*HSTR; i += THREADS) {
    h0A[0][i] = 0; h0A[1][i] = 0; h1A[0][i] = 0; h1A[1][i] = 0;
  }
  if (tid < BT) xA[tid*32 + 8] = (short)0x3F80;   // 1.0 bf16 -> layer0 bias slot
  if (tid < HD) sLs[tid] = gma[tid] * rsqrtf(var[tid] + 1e-5f);
  if (tid < 260) { int o = tid / 65, p = tid % 65; W2L[tid] = (p < 64) ? W2[o*64 + p] : 0.f; }
  if (tid < 32) WfL[tid] = Wf[tid];
  if (tid < 4)  b2L[tid] = b2[tid];
  if (tid < 8)  bfL[tid] = bfv[tid];
  for (int i = tid; i < 512*HD; i += THREADS) {   // Whh0 -> LDS, gate-permuted
    int col = i >> 7, k = i & 127;
    int og = (col & 3)*HD + (col >> 2);
    WhhL[col*WSTR + k] = f2bf(Whh0[og*HD + k]);
  }

  // ---- register-resident weights (bf16), gate-permuted ----
  bf16x8 wih0f[NT], wih1f[NT][4], whh1f[NT][4];
  float b1sum[NT];
  #pragma unroll
  for (int nt = 0; nt < NT; nt++) {
    int col = w*64 + nt*16 + ln;
    int og  = (col & 3)*HD + (col >> 2);
    // Wih0 frag (K padded to 32; k==8 carries layer0 bias, matching xA col8=1)
    {
      bf16x8 r;
      #pragma unroll
      for (int j = 0; j < 8; j++) {
        int k = q*8 + j;
        float v = 0.f;
        if (k < 8) v = Wih0[og*8 + k];
        else if (k == 8) v = bih0[og] + bhh0[og];
        r[j] = f2bf(v);
      }
      wih0f[nt] = r;
    }
    #pragma unroll
    for (int kk = 0; kk < 4; kk++) {
      int k0 = kk*32 + q*8;
      wih1f[nt][kk] = load8(Wih1 + og*HD + k0);
      whh1f[nt][kk] = load8(Whh1 + og*HD + k0);
    }
    b1sum[nt] = bih1[og] + bhh1[og];
  }
  __syncthreads();  // phase A visible (sLs for below)

  // ---- phase B: needs sLs ----
  if (tid < 64) {
    float acc = b1[tid];
    for (int j = 0; j < HD; j++)
      acc += (bta[j] - mu[j]*sLs[j]) * W1[tid*HD + j];
    b1cL[tid] = acc;
  }
  // per-wave BN-folded W1 B-frags (only waves 0..3 used in decoder)
  bf16x8 w1f[4];
  #pragma unroll
  for (int kk = 0; kk < 4; kk++) {
    bf16x8 r;
    if (w < 4) {
      int p = w*16 + ln;
      #pragma unroll
      for (int j = 0; j < 8; j++) {
        int k = kk*32 + q*8 + j;
        r[j] = f2bf(sLs[k] * W1[p*HD + k]);
      }
    } else {
      #pragma unroll
      for (int j = 0; j < 8; j++) r[j] = 0;
    }
    w1f[kk] = r;
  }
  __syncthreads();  // b1cL ready; all init done

  float c0s[NT], c1s[NT];
  #pragma unroll
  for (int nt = 0; nt < NT; nt++) { c0s[nt] = 0.f; c1s[nt] = 0.f; }

  const int aoffX = ln*32   + q*8;   // x A-frag offset (shorts)
  const int aoffH = ln*HSTR + q*8;   // h A-frag offset, + kk*32
  const int mrow  = q*4 + (l & 3);   // row after quad-transpose
  const int jbase = w*16 + ((l >> 2) & 3);

  // -------- layer 0: z = x@Wih0^T (+bias) + h0@Whh0^T (Whh0 from LDS) --------
  auto layer0 = [&](const short* h0r, short* h0w) {
    bf16x8 ax = *(const bf16x8*)(xA + aoffX);
    bf16x8 ah[4];
    #pragma unroll
    for (int kk = 0; kk < 4; kk++)
      ah[kk] = *(const bf16x8*)(h0r + aoffH + kk*32);
    #pragma unroll
    for (int nt = 0; nt < NT; nt++) {
      const int cb = (w*64 + nt*16 + ln)*WSTR + q*8;
      bf16x8 wb0 = *(const bf16x8*)(WhhL + cb);
      bf16x8 wb1 = *(const bf16x8*)(WhhL + cb + 32);
      bf16x8 wb2 = *(const bf16x8*)(WhhL + cb + 64);
      bf16x8 wb3 = *(const bf16x8*)(WhhL + cb + 96);
      f32x4 a = {0.f,0.f,0.f,0.f};
      a = __builtin_amdgcn_mfma_f32_16x16x32_bf16(ax,    wih0f[nt], a, 0, 0, 0);
      a = __builtin_amdgcn_mfma_f32_16x16x32_bf16(ah[0], wb0, a, 0, 0, 0);
      a = __builtin_amdgcn_mfma_f32_16x16x32_bf16(ah[1], wb1, a, 0, 0, 0);
      a = __builtin_amdgcn_mfma_f32_16x16x32_bf16(ah[2], wb2, a, 0, 0, 0);
      a = __builtin_amdgcn_mfma_f32_16x16x32_bf16(ah[3], wb3, a, 0, 0, 0);
      float v0 = a[0], v1 = a[1], v2 = a[2], v3 = a[3];
      quad_transpose(v0, v1, v2, v3, l);
      float ii = fsig(v0), ff = fsig(v1), gg = ftanh(v2), oo = fsig(v3);
      float c = ff*c0s[nt] + ii*gg;
      c0s[nt] = c;
      float h = oo * ftanh(c);
      h0w[mrow*HSTR + jbase + nt*4] = f2bf(h);
    }
  };

  // -------- layer 1: z = h0new@Wih1^T + h1@Whh1^T + b (weights in regs) -----
  auto layer1 = [&](const short* h0n, const short* h1r, short* h1w) {
    bf16x8 a0[4], a1k[4];
    #pragma unroll
    for (int kk = 0; kk < 4; kk++) {
      a0[kk]  = *(const bf16x8*)(h0n + aoffH + kk*32);
      a1k[kk] = *(const bf16x8*)(h1r + aoffH + kk*32);
    }
    #pragma unroll
    for (int nt = 0; nt < NT; nt++) {
      f32x4 a; a[0]=a[1]=a[2]=a[3]=b1sum[nt];
      #pragma unroll
      for (int kk = 0; kk < 4; kk++) {
        a = __builtin_amdgcn_mfma_f32_16x16x32_bf16(a0[kk],  wih1f[nt][kk], a, 0, 0, 0);
        a = __builtin_amdgcn_mfma_f32_16x16x32_bf16(a1k[kk], whh1f[nt][kk], a, 0, 0, 0);
      }
      float v0 = a[0], v1 = a[1], v2 = a[2], v3 = a[3];
      quad_transpose(v0, v1, v2, v3, l);
      float ii = fsig(v0), ff = fsig(v1), gg = ftanh(v2), oo = fsig(v3);
      float c = ff*c1s[nt] + ii*gg;
      c1s[nt] = c;
      float h = oo * ftanh(c);
      h1w[mrow*HSTR + jbase + nt*4] = f2bf(h);
    }
  };

  // ================= encoder (x[t+1] prefetched under layer0) =================
  {
    const int b = tid >> 3, i = tid & 7;
    if (tid < 128) xA[b*32 + i] = f2bf(xg[(size_t)(gb0 + b)*(TLEN*8) + 0*8 + i]);
    __syncthreads();
  }
  auto enc_iter = [&](int tt, const short* h0r, short* h0w, const short* h1r, short* h1w) {
    const int b = tid >> 3, i = tid & 7;
    const bool pf = (tt + 1 < TLEN) && (tid < 128);
    float xp = 0.f;
    if (pf) xp = xg[(size_t)(gb0 + b)*(TLEN*8) + (tt+1)*8 + i];   // in flight under layer0
    layer0(h0r, h0w);
    __syncthreads();           // h0 new visible; all layer0 xA reads done
    if (pf) xA[b*32 + i] = f2bf(xp);
    layer1(h0w, h1r, h1w);
    __syncthreads();           // h1 new + xA(t+1) visible
  };
  for (int t = 0; t < TLEN; t += 2) {
    enc_iter(t,     h0A[0], h0A[1], h1A[0], h1A[1]);
    enc_iter(t + 1, h0A[1], h0A[0], h1A[1], h1A[0]);
  }
  // xA holds x[:, T-1, :] == first decoder input; state in buffers [0].

  // ================= decoder =================
  for (int s = 0; s < ps; s++) {
    int rb = s & 1;
    __syncthreads();  // xA + buffer turnover ready
    layer0(h0A[rb], h0A[rb^1]);
    __syncthreads();
    layer1(h0A[rb^1], h1A[rb], h1A[rb^1]);
    const short* h1n = h1A[rb^1];
    __syncthreads();  // h1 new visible to all waves
    // ---- a1 = relu(h1 @ (bn-folded W1)^T + b1c): MFMA on waves 0..3
    if (w < 4) {
      f32x4 aa = {0.f,0.f,0.f,0.f};
      #pragma unroll
      for (int kk = 0; kk < 4; kk++) {
        bf16x8 ahn = *(const bf16x8*)(h1n + aoffH + kk*32);
        aa = __builtin_amdgcn_mfma_f32_16x16x32_bf16(ahn, w1f[kk], aa, 0, 0, 0);
      }
      float bb = b1cL[w*16 + ln];
      #pragma unroll
      for (int r = 0; r < 4; r++)
        a1L[(w*16 + ln)*16 + q*4 + r] = fmaxf(aa[r] + bb, 0.f);
    }
    __syncthreads();
    // ---- out = a1 @ W2^T + b2 ; store
    if (tid < 64) {
      int b = tid & 15, o = tid >> 4;
      float acc2 = b2L[o];
      for (int p = 0; p < 64; p++)
        acc2 += a1L[p*16 + b] * W2L[o*65 + p];
      dout[(size_t)(gb0 + b)*(ps*4) + s*4 + o] = acc2;
      outL[o*16 + b] = acc2;
    }
    __syncthreads();
    // ---- xin = out @ Wf^T + bf -> next x
    if (tid < 128) {
      int b = tid >> 3, i = tid & 7;
      float v = bfL[i];
      #pragma unroll
      for (int o = 0; o < 4; o++) v += outL[o*16 + b] * WfL[i*4 + o];
      xA[b*32 + i] = f2bf(v);
    }
  }
}

extern "C" void kernel_launch(void* const* d_in, const int* in_sizes, int n_in,
                              void* d_out, int out_size, void* d_ws, size_t ws_size,
                              hipStream_t stream) {
  (void)in_sizes; (void)n_in; (void)d_ws; (void)ws_size; (void)out_size;
  lstm_kernel<<<dim3(4096/BT), dim3(THREADS), 0, stream>>>(
      (const float*)d_in[0],  (const float*)d_in[1],  (const float*)d_in[2],
      (const float*)d_in[3],  (const float*)d_in[4],  (const float*)d_in[5],
      (const float*)d_in[6],  (const float*)d_in[7],  (const float*)d_in[8],
      (const float*)d_in[9],  (const float*)d_in[10], (const float*)d_in[11],
      (const float*)d_in[12], (const float*)d_in[13], (const float*)d_in[14],
      (const float*)d_in[15], (const float*)d_in[16], (const float*)d_in[17],
      (const float*)d_in[18], (const int*)d_in[19],   (float*)d_out);
}